// Round 19
// baseline (696.355 us; speedup 1.0000x reference)
//
#include <hip/hip_runtime.h>
#include <hip/hip_bf16.h>

#define IN_F 4096
#define OUT_F 11008
#define GSIZE 128
#define M_TOTAL 8192

typedef float f32x4 __attribute__((ext_vector_type(4)));
typedef float f32x16 __attribute__((ext_vector_type(16)));
typedef unsigned short u16x8 __attribute__((ext_vector_type(8)));
typedef unsigned int u32x4 __attribute__((ext_vector_type(4)));
typedef __bf16 bf16x8 __attribute__((ext_vector_type(8)));

#define ASG __attribute__((address_space(1)))
#define ASL __attribute__((address_space(3)))

__device__ __forceinline__ unsigned short f2bf(float f) {
    union { float f; unsigned int u; } v;
    v.f = f;
    unsigned int u = v.u;
    unsigned int r = (u + 0x7fffu + ((u >> 16) & 1u)) >> 16;
    return (unsigned short)r;
}

// ---------------------------------------------------------------------------
// Fragment-subtile global layout (matches MFMA 32x32x16 operand order):
//   subtile (f, kf) = 32 rows x 16 k, 1024 B at ((f * (K/16) + kf) * 1024).
//   lane l = (q2*32 + r): holds elem[row = f*32 + r][k = kf*16 + q2*8 .. +8].
// ---------------------------------------------------------------------------

// Pass 0: x fp32 [M][K] -> xb fragment order [M/32][K/16][64][8].
__global__ void convert_x_frag_kernel(const float* __restrict__ x,
                                      unsigned short* __restrict__ xb) {
    const int mf = blockIdx.x;            // 0..255
    const int r  = threadIdx.x >> 3;      // 0..31
    const int kb = (threadIdx.x & 7) * 8; // 0..56
    const int k0 = blockIdx.y * 512;
    const float* src = x + (size_t)(mf * 32 + r) * IN_F;
    unsigned short* dst = xb + (size_t)mf * (IN_F / 16) * 512;
#pragma unroll
    for (int kk = 0; kk < 512; kk += 64) {
        const int k = k0 + kk + kb;
        f32x4 a = *(const f32x4*)(src + k);
        f32x4 b = *(const f32x4*)(src + k + 4);
        u16x8 v;
#pragma unroll
        for (int e = 0; e < 4; ++e) {
            v[e]     = f2bf(a[e]);
            v[e + 4] = f2bf(b[e]);
        }
        const int kf = k >> 4, q2 = (k >> 3) & 1;
        *(u16x8*)(dst + (size_t)kf * 512 + (q2 * 32 + r) * 8) = v;
    }
}

// Pass 1: int4 weights -> wt fragment order [N/32][K/16][64][8].
__global__ void dequant_w_frag_kernel(const int* __restrict__ qw,
                                      const float* __restrict__ scales,
                                      const float* __restrict__ zeros,
                                      unsigned short* __restrict__ wt) {
    const int n  = blockIdx.x * 256 + threadIdx.x;   // 0..11007
    const int k0 = blockIdx.y * 32;
    const int g  = k0 >> 7;
    const float s = scales[(size_t)g * OUT_F + n];
    const float z = zeros[(size_t)g * OUT_F + n];

    unsigned short outv[32];
#pragma unroll
    for (int i = 0; i < 16; ++i) {
        int q = qw[(size_t)(k0 / 2 + i) * OUT_F + n];
        float lo = (float)((q & 15) - 8) * s + z;        // even k = low nibble
        float hi = (float)(((q >> 4) & 15) - 8) * s + z; // odd k  = high nibble
        outv[2 * i]     = f2bf(lo);
        outv[2 * i + 1] = f2bf(hi);
    }
    const int nf = n >> 5, r32 = n & 31;
    unsigned short* base = wt + (size_t)nf * (IN_F / 16) * 512 +
                           (size_t)(k0 >> 4) * 512;
    const u16x8* sv = (const u16x8*)outv;
#pragma unroll
    for (int c = 0; c < 4; ++c)   // chunk c: k = k0 + c*8 .. +8
        *(u16x8*)(base + (c >> 1) * 512 + ((c & 1) * 32 + r32) * 8) = sv[c];
}

// Pass 1b (fallback path): row-major W^T bf16 [OUT_F][IN_F].
__global__ void dequant_w_rowmajor_kernel(const int* __restrict__ qw,
                                          const float* __restrict__ scales,
                                          const float* __restrict__ zeros,
                                          unsigned short* __restrict__ wt) {
    const int n  = blockIdx.x * 256 + threadIdx.x;
    const int k0 = blockIdx.y * 32;
    const int g  = k0 >> 7;
    const float s = scales[(size_t)g * OUT_F + n];
    const float z = zeros[(size_t)g * OUT_F + n];

    unsigned short outv[32];
#pragma unroll
    for (int i = 0; i < 16; ++i) {
        int q = qw[(size_t)(k0 / 2 + i) * OUT_F + n];
        float lo = (float)((q & 15) - 8) * s + z;
        float hi = (float)(((q >> 4) & 15) - 8) * s + z;
        outv[2 * i]     = f2bf(lo);
        outv[2 * i + 1] = f2bf(hi);
    }
    u16x8* dst = (u16x8*)(wt + (size_t)n * IN_F + k0);
    const u16x8* src = (const u16x8*)outv;
#pragma unroll
    for (int i = 0; i < 4; ++i) dst[i] = src[i];
}

// ---------------------------------------------------------------------------
// Pass 2 (round 19): round-17 2-barrier zoning + round-18 no-setprio.
// Per tile t (buf P=t&1):
//  ZA: QUAD(kc0,set0); READ(P,kc1,set1); QUAD(kc1,set1); READ(P,kc2,set0);
//      STG kc0(t+2)->P [g2]; STG kc3(t+1)->!P                        | BAR
//  ZB: QUAD(kc2,set0); READ(P,kc3,set1); QUAD(kc3,set1);
//      STG kc1(t+2)->P [g2]; STG kc2(t+2)->P [g2];
//      vmcnt(4|0); pre-read kc0(t+1)->set0                           | BAR
// WAR: kc0(t+2)->P after kc0(t) pre-read ZB(t-1) ✓; kc3(t+1)->!P after
// kc3(t-1) read ZB(t-1) ✓; kc1/kc2(t+2)->P after ZA(t) reads ✓.
// RAW: stage order ZA:{kc0(t+2),kc3(t+1)} ZB:{kc1,kc2(t+2)}; vmcnt(4) at
// ZB(t) retires through ZA(t) => all of tile t+1 resident before pre-read ✓.
// Tail: vmcnt(0). No setprio (r18: +5pp MfmaUtil, lockstep waves interleave).
// Chunked XCD swizzle (FETCH 0.55 GB) + nt-stores retained.
// ---------------------------------------------------------------------------
__global__ __launch_bounds__(512, 1)
void gemm_kc5(const unsigned short* __restrict__ xb,   // frag order
              const unsigned short* __restrict__ wt,   // frag order
              const float* __restrict__ bias,
              float* __restrict__ out) {
    constexpr int NT = IN_F / 64;  // 64 K-tiles
    constexpr int NKF = IN_F / 16; // 256 k-frags
    __shared__ __attribute__((aligned(128))) unsigned short lds[65536]; // 128 KiB

    // chunked XCD swizzle: XCD x owns m-band [4x,4x+4); n slow within band
    const int bid = (int)blockIdx.x;
    const int xcd = bid & 7;
    const int l   = bid >> 3;          // 0..171
    const int m0 = (xcd * 4 + (l & 3)) * 256;
    const int n0 = (l >> 2) * 256;

    const int tid  = threadIdx.x;
    const int lane = tid & 63;
    const int wave = tid >> 6;       // 0..7
    const int wr = wave >> 2;        // 0..1  (M half)
    const int wc = wave & 3;         // 0..3  (N quarter)
    const int r32 = lane & 31;
    const int q2  = lane >> 5;

    const ASG char* xbc = (const ASG char*)xb;
    const ASG char* wtc = (const ASG char*)wt;
    ASL char* ldsc = (ASL char*)lds;

    // ---- staging streams: stream kc stages subtile (f=wave, kc) of A and
    // (cf=wave, kc) of B; coalesced 1024-B bursts; +4096 B per use (1 tile).
    const int mfb = m0 >> 5;
    const int nfb = n0 >> 5;
    unsigned int oA[4], oB[4];
    int dA[4], dB[4];
#pragma unroll
    for (int kc = 0; kc < 4; ++kc) {
        oA[kc] = (unsigned int)(((mfb + wave) * NKF + kc) * 1024 + lane * 16);
        oB[kc] = (unsigned int)(((nfb + wave) * NKF + kc) * 1024 + lane * 16);
        dA[kc] = (wave * 4 + kc) * 1024;
        dB[kc] = 32768 + (wave * 4 + kc) * 1024;
    }

#define STG_Z(KC, P)                                                           \
    do {                                                                       \
        __builtin_amdgcn_global_load_lds(                                      \
            (ASG const unsigned int*)(xbc + oA[(KC)]),                         \
            (ASL unsigned int*)(ldsc + dA[(KC)] + (P) * 65536), 16, 0, 0);     \
        __builtin_amdgcn_global_load_lds(                                      \
            (ASG const unsigned int*)(wtc + oB[(KC)]),                         \
            (ASL unsigned int*)(ldsc + dB[(KC)] + (P) * 65536), 16, 0, 0);     \
        oA[(KC)] += 4096;                                                      \
        oB[(KC)] += 4096;                                                      \
    } while (0)

#define BAR()                                                                  \
    do {                                                                       \
        __builtin_amdgcn_sched_barrier(0);                                     \
        __builtin_amdgcn_s_barrier();                                          \
        __builtin_amdgcn_sched_barrier(0);                                     \
    } while (0)

    bf16x8 afR[2][4];   // [set][m-frag]
    bf16x8 bfR[2][2];   // [set][n-frag]
    f32x16 acc[4][2];
#pragma unroll
    for (int i = 0; i < 4; ++i)
#pragma unroll
        for (int j = 0; j < 2; ++j) acc[i][j] = (f32x16)0.0f;

    // read all 6 operand frags of one kc into register set S
#define READ_KC(P, KC, S)                                                      \
    do {                                                                       \
        const unsigned short* _b = lds + (P) * 32768 + lane * 8;               \
        _Pragma("unroll") for (int _m = 0; _m < 4; ++_m)                       \
            afR[S][_m] = *(const bf16x8*)(_b +                                 \
                (((wr * 4 + _m) * 4 + (KC)) << 9));                            \
        _Pragma("unroll") for (int _n = 0; _n < 2; ++_n)                       \
            bfR[S][_n] = *(const bf16x8*)(_b + 16384 +                         \
                (((wc * 2 + _n) * 4 + (KC)) << 9));                            \
    } while (0)

    // 8 INDEPENDENT MFMA — no setprio
#define QUAD_KC(S)                                                             \
    do {                                                                       \
        _Pragma("unroll") for (int _m = 0; _m < 4; ++_m)                       \
        _Pragma("unroll") for (int _n = 0; _n < 2; ++_n)                       \
            acc[_m][_n] = __builtin_amdgcn_mfma_f32_32x32x16_bf16(             \
                afR[S][_m], bfR[S][_n], acc[_m][_n], 0, 0, 0);                 \
    } while (0)

    // ---- prologue: stage tile0 (all kc) -> buf0, tile1 {kc0,kc1,kc2} -> buf1
    // (kc3(t1) arrives in ZA(t0)). 14 insts; vmcnt(6) -> tile0 resident.
#pragma unroll
    for (int kc = 0; kc < 4; ++kc) STG_Z(kc, 0);
    STG_Z(0, 1); STG_Z(1, 1); STG_Z(2, 1);
    __builtin_amdgcn_sched_barrier(0);
    asm volatile("s_waitcnt vmcnt(6)" ::: "memory");
    BAR();
    READ_KC(0, 0, 0);   // tile0 kc0 -> set0
    BAR();              // all waves done reading kc0 before ZA stages over it

#pragma unroll 1
    for (int tt = 0; tt < NT; tt += 2) {
        const bool g2 = (tt + 2 < NT);
        const bool g3 = (tt + 3 < NT);
        // ================= tile tt (buf 0) =================
        // ZA
        QUAD_KC(0);
        READ_KC(0, 1, 1);
        QUAD_KC(1);
        READ_KC(0, 2, 0);
        if (g2) STG_Z(0, 0);               // kc0(tt+2) -> buf0
        STG_Z(3, 1);                       // kc3(tt+1) -> buf1 (tt+1<NT always)
        BAR();
        // ZB
        QUAD_KC(0);
        READ_KC(0, 3, 1);
        QUAD_KC(1);
        if (g2) { STG_Z(1, 0); STG_Z(2, 0); }  // kc1,kc2(tt+2) -> buf0
        __builtin_amdgcn_sched_barrier(0);
        if (g2) {
            asm volatile("s_waitcnt vmcnt(4)" ::: "memory");
        } else {
            asm volatile("s_waitcnt vmcnt(0)" ::: "memory");
        }
        __builtin_amdgcn_sched_barrier(0);
        READ_KC(1, 0, 0);                  // pre-read tile tt+1 kc0 -> set0
        BAR();
        // ================= tile tt+1 (buf 1) =================
        // ZA
        QUAD_KC(0);
        READ_KC(1, 1, 1);
        QUAD_KC(1);
        READ_KC(1, 2, 0);
        if (g3) STG_Z(0, 1);               // kc0(tt+3) -> buf1
        if (g2) STG_Z(3, 0);               // kc3(tt+2) -> buf0
        BAR();
        // ZB
        QUAD_KC(0);
        READ_KC(1, 3, 1);
        QUAD_KC(1);
        if (g3) { STG_Z(1, 1); STG_Z(2, 1); }  // kc1,kc2(tt+3) -> buf1
        __builtin_amdgcn_sched_barrier(0);
        if (g3) {
            asm volatile("s_waitcnt vmcnt(4)" ::: "memory");
        } else {
            asm volatile("s_waitcnt vmcnt(0)" ::: "memory");
        }
        __builtin_amdgcn_sched_barrier(0);
        if (g2) READ_KC(0, 0, 0);          // pre-read tile tt+2 kc0 -> set0
        BAR();
    }

    // ---- epilogue: 32x32 C/D layout col = lane&31,
    //      row = (reg&3) + 8*(reg>>2) + 4*(lane>>5); non-temporal stores.
#pragma unroll
    for (int nf = 0; nf < 2; ++nf) {
        const int col = n0 + wc * 64 + nf * 32 + r32;
        const float bv = bias[col];
#pragma unroll
        for (int mf = 0; mf < 4; ++mf) {
            const int row0 = m0 + wr * 128 + mf * 32 + q2 * 4;
#pragma unroll
            for (int r = 0; r < 16; ++r) {
                const int row = row0 + (r & 3) + ((r >> 2) << 3);
                __builtin_nontemporal_store(acc[mf][nf][r] + bv,
                                            &out[(size_t)row * OUT_F + col]);
            }
        }
    }
#undef STG_Z
#undef BAR
#undef READ_KC
#undef QUAD_KC
}

// ---------------------------------------------------------------------------
// Fallback GEMM (reg-staged 128x128, row-major operands), for small ws.
// ---------------------------------------------------------------------------
template <bool PREW>
__global__ __launch_bounds__(256, 2)
void gemm_kernel(const float* __restrict__ x,
                 const unsigned short* __restrict__ wt,
                 const int* __restrict__ qw,
                 const float* __restrict__ scales,
                 const float* __restrict__ zeros,
                 const float* __restrict__ bias,
                 float* __restrict__ out) {
    constexpr int BM = 128, BN = 128, BK = 64;
    constexpr int LDK = BK + 8;
    constexpr int NT = IN_F / BK;

    __shared__ unsigned short As[BM * LDK];
    __shared__ unsigned short Bs[BN * LDK];

    const int bid = blockIdx.x;
    constexpr int NB_N = OUT_F / BN;
    const int m0 = (bid / NB_N) * BM;
    const int n0 = (bid % NB_N) * BN;

    const int tid  = threadIdx.x;
    const int lane = tid & 63;
    const int wave = tid >> 6;
    const int wr = wave >> 1, wc = wave & 1;

    const int st_row = tid >> 3;
    const int st_col = (tid & 7) * 8;

    f32x4 areg[4][2];
    u32x4 breg[4];
    int   qreg[16];
    float s_, z_;
    const int b_n  = tid & 127;
    const int b_kp = (tid >> 7) * 16;

    auto load_tile = [&](int kt) {
        {
            const float* base = x + (size_t)m0 * IN_F + (size_t)kt * BK + st_col;
#pragma unroll
            for (int p = 0; p < 4; ++p) {
                const float* rp = base + (size_t)(p * 32 + st_row) * IN_F;
                areg[p][0] = *(const f32x4*)rp;
                areg[p][1] = *(const f32x4*)(rp + 4);
            }
        }
        if constexpr (PREW) {
            const unsigned short* base = wt + (size_t)n0 * IN_F + (size_t)kt * BK + st_col;
#pragma unroll
            for (int p = 0; p < 4; ++p)
                breg[p] = *(const u32x4*)(base + (size_t)(p * 32 + st_row) * IN_F);
        } else {
            const int kp0 = kt * (BK / 2) + b_kp;
#pragma unroll
            for (int i = 0; i < 16; ++i)
                qreg[i] = qw[(size_t)(kp0 + i) * OUT_F + n0 + b_n];
            const int g = (kt * BK) >> 7;
            s_ = scales[(size_t)g * OUT_F + n0 + b_n];
            z_ = zeros[(size_t)g * OUT_F + n0 + b_n];
        }
    };

    auto write_lds = [&]() {
#pragma unroll
        for (int p = 0; p < 4; ++p) {
            u16x8 v;
#pragma unroll
            for (int e = 0; e < 4; ++e) {
                v[e]     = f2bf(areg[p][0][e]);
                v[e + 4] = f2bf(areg[p][1][e]);
            }
            *(u16x8*)(&As[(p * 32 + st_row) * LDK + st_col]) = v;
        }
        if constexpr (PREW) {
#pragma unroll
            for (int p = 0; p < 4; ++p)
                *(u32x4*)(&Bs[(p * 32 + st_row) * LDK + st_col]) = breg[p];
        } else {
            unsigned short tmp[32];
#pragma unroll
            for (int i = 0; i < 16; ++i) {
                int q = qreg[i];
                tmp[2 * i]     = f2bf((float)((q & 15) - 8) * s_ + z_);
                tmp[2 * i + 1] = f2bf((float)(((q >> 4) & 15) - 8) * s_ + z_);
            }
            const u16x8* srcv = (const u16x8*)tmp;
#pragma unroll
            for (int i = 0; i < 4; ++i)
                *(u16x8*)(&Bs[b_n * LDK + 2 * b_kp + 8 * i]) = srcv[i];
        }
    };

    f32x4 acc[4][4];
#pragma unroll
    for (int i = 0; i < 4; ++i)
#pragma unroll
        for (int j = 0; j < 4; ++j) acc[i][j] = (f32x4)0.0f;

    load_tile(0);

#pragma unroll 1
    for (int kt = 0; kt < NT; ++kt) {
        __syncthreads();
        write_lds();
        __syncthreads();
        if (kt + 1 < NT) load_tile(kt + 1);

#pragma unroll
        for (int kk = 0; kk < 2; ++kk) {
            const int kidx = kk * 32 + ((lane >> 4) << 3);
            bf16x8 afv[4], bfv[4];
#pragma unroll
            for (int i = 0; i < 4; ++i)
                afv[i] = *(const bf16x8*)(&As[(wr * 64 + i * 16 + (lane & 15)) * LDK + kidx]);
#pragma unroll
            for (int j = 0; j < 4; ++j)
                bfv[j] = *(const bf16x8*)(&Bs[(wc * 64 + j * 16 + (lane & 15)) * LDK + kidx]);
#pragma unroll
            for (int i = 0; i < 4; ++i)
#pragma unroll
                for (int j = 0; j < 4; ++j)
                    acc[i][j] = __builtin_amdgcn_mfma_f32_16x16x32_bf16(afv[i], bfv[j], acc[i][j], 0, 0, 0);
        }
    }

    const int orow_base = m0 + wr * 64 + ((lane >> 4) << 2);
    const int ocol_base = n0 + wc * 64 + (lane & 15);
#pragma unroll
    for (int j = 0; j < 4; ++j) {
        const float bv = bias[ocol_base + j * 16];
#pragma unroll
        for (int i = 0; i < 4; ++i) {
#pragma unroll
            for (int q = 0; q < 4; ++q) {
                out[(size_t)(orow_base + i * 16 + q) * OUT_F + (ocol_base + j * 16)] =
                    acc[i][j][q] + bv;
            }
        }
    }
}

// ---------------------------------------------------------------------------
extern "C" void kernel_launch(void* const* d_in, const int* in_sizes, int n_in,
                              void* d_out, int out_size, void* d_ws, size_t ws_size,
                              hipStream_t stream) {
    const float* x      = (const float*)d_in[0];
    const int*   qw     = (const int*)d_in[1];
    const float* scales = (const float*)d_in[2];
    const float* zeros  = (const float*)d_in[3];
    const float* bias   = (const float*)d_in[4];
    float* out = (float*)d_out;

    const size_t wt_bytes = (size_t)OUT_F * IN_F * sizeof(unsigned short);   // 90.2 MB
    const size_t xb_bytes = (size_t)M_TOTAL * IN_F * sizeof(unsigned short); // 67.1 MB

    if (ws_size >= wt_bytes + xb_bytes) {
        unsigned short* wt = (unsigned short*)d_ws;
        unsigned short* xb = (unsigned short*)((char*)d_ws + wt_bytes);
        convert_x_frag_kernel<<<dim3(M_TOTAL / 32, 8), 256, 0, stream>>>(x, xb);
        dequant_w_frag_kernel<<<dim3(OUT_F / 256, IN_F / 32), 256, 0, stream>>>(qw, scales, zeros, wt);
        gemm_kc5<<<(M_TOTAL / 256) * (OUT_F / 256), 512, 0, stream>>>(xb, wt, bias, out);
    } else if (ws_size >= wt_bytes) {
        unsigned short* wt = (unsigned short*)d_ws;
        dequant_w_rowmajor_kernel<<<dim3(OUT_F / 256, IN_F / 32), 256, 0, stream>>>(qw, scales, zeros, wt);
        gemm_kernel<true><<<(M_TOTAL / 128) * (OUT_F / 128), 256, 0, stream>>>(x, wt, qw, scales, zeros, bias, out);
    } else {
        gemm_kernel<false><<<(M_TOTAL / 128) * (OUT_F / 128), 256, 0, stream>>>(x, nullptr, qw, scales, zeros, bias, out);
    }
}

// Round 20
// 681.116 us; speedup vs baseline: 1.0224x; 1.0224x over previous
//
#include <hip/hip_runtime.h>
#include <hip/hip_bf16.h>

#define IN_F 4096
#define OUT_F 11008
#define GSIZE 128
#define M_TOTAL 8192

typedef float f32x4 __attribute__((ext_vector_type(4)));
typedef float f32x16 __attribute__((ext_vector_type(16)));
typedef unsigned short u16x8 __attribute__((ext_vector_type(8)));
typedef unsigned int u32x4 __attribute__((ext_vector_type(4)));
typedef __bf16 bf16x8 __attribute__((ext_vector_type(8)));

#define ASG __attribute__((address_space(1)))
#define ASL __attribute__((address_space(3)))

__device__ __forceinline__ unsigned short f2bf(float f) {
    union { float f; unsigned int u; } v;
    v.f = f;
    unsigned int u = v.u;
    unsigned int r = (u + 0x7fffu + ((u >> 16) & 1u)) >> 16;
    return (unsigned short)r;
}

// ---------------------------------------------------------------------------
// Fragment-subtile global layout (matches MFMA 32x32x16 operand order):
//   subtile (f, kf) = 32 rows x 16 k, 1024 B at ((f * (K/16) + kf) * 1024).
//   lane l = (q2*32 + r): holds elem[row = f*32 + r][k = kf*16 + q2*8 .. +8].
// ---------------------------------------------------------------------------

// Pass 0: x fp32 [M][K] -> xb fragment order [M/32][K/16][64][8].
__global__ void convert_x_frag_kernel(const float* __restrict__ x,
                                      unsigned short* __restrict__ xb) {
    const int mf = blockIdx.x;            // 0..255
    const int r  = threadIdx.x >> 3;      // 0..31
    const int kb = (threadIdx.x & 7) * 8; // 0..56
    const int k0 = blockIdx.y * 512;
    const float* src = x + (size_t)(mf * 32 + r) * IN_F;
    unsigned short* dst = xb + (size_t)mf * (IN_F / 16) * 512;
#pragma unroll
    for (int kk = 0; kk < 512; kk += 64) {
        const int k = k0 + kk + kb;
        f32x4 a = *(const f32x4*)(src + k);
        f32x4 b = *(const f32x4*)(src + k + 4);
        u16x8 v;
#pragma unroll
        for (int e = 0; e < 4; ++e) {
            v[e]     = f2bf(a[e]);
            v[e + 4] = f2bf(b[e]);
        }
        const int kf = k >> 4, q2 = (k >> 3) & 1;
        *(u16x8*)(dst + (size_t)kf * 512 + (q2 * 32 + r) * 8) = v;
    }
}

// Pass 1: int4 weights -> wt fragment order [N/32][K/16][64][8].
__global__ void dequant_w_frag_kernel(const int* __restrict__ qw,
                                      const float* __restrict__ scales,
                                      const float* __restrict__ zeros,
                                      unsigned short* __restrict__ wt) {
    const int n  = blockIdx.x * 256 + threadIdx.x;   // 0..11007
    const int k0 = blockIdx.y * 32;
    const int g  = k0 >> 7;
    const float s = scales[(size_t)g * OUT_F + n];
    const float z = zeros[(size_t)g * OUT_F + n];

    unsigned short outv[32];
#pragma unroll
    for (int i = 0; i < 16; ++i) {
        int q = qw[(size_t)(k0 / 2 + i) * OUT_F + n];
        float lo = (float)((q & 15) - 8) * s + z;        // even k = low nibble
        float hi = (float)(((q >> 4) & 15) - 8) * s + z; // odd k  = high nibble
        outv[2 * i]     = f2bf(lo);
        outv[2 * i + 1] = f2bf(hi);
    }
    const int nf = n >> 5, r32 = n & 31;
    unsigned short* base = wt + (size_t)nf * (IN_F / 16) * 512 +
                           (size_t)(k0 >> 4) * 512;
    const u16x8* sv = (const u16x8*)outv;
#pragma unroll
    for (int c = 0; c < 4; ++c)   // chunk c: k = k0 + c*8 .. +8
        *(u16x8*)(base + (c >> 1) * 512 + ((c & 1) * 32 + r32) * 8) = sv[c];
}

// Pass 1b (fallback path): row-major W^T bf16 [OUT_F][IN_F].
__global__ void dequant_w_rowmajor_kernel(const int* __restrict__ qw,
                                          const float* __restrict__ scales,
                                          const float* __restrict__ zeros,
                                          unsigned short* __restrict__ wt) {
    const int n  = blockIdx.x * 256 + threadIdx.x;
    const int k0 = blockIdx.y * 32;
    const int g  = k0 >> 7;
    const float s = scales[(size_t)g * OUT_F + n];
    const float z = zeros[(size_t)g * OUT_F + n];

    unsigned short outv[32];
#pragma unroll
    for (int i = 0; i < 16; ++i) {
        int q = qw[(size_t)(k0 / 2 + i) * OUT_F + n];
        float lo = (float)((q & 15) - 8) * s + z;
        float hi = (float)(((q >> 4) & 15) - 8) * s + z;
        outv[2 * i]     = f2bf(lo);
        outv[2 * i + 1] = f2bf(hi);
    }
    u16x8* dst = (u16x8*)(wt + (size_t)n * IN_F + k0);
    const u16x8* src = (const u16x8*)outv;
#pragma unroll
    for (int i = 0; i < 4; ++i) dst[i] = src[i];
}

// ---------------------------------------------------------------------------
// Pass 2 (final, = round 18 best): 256x256 bf16 GEMM, mfma_f32_32x32x16,
// kc-sliced 4-zone schedule, counted vmcnt, NO setprio.
//  Z0: QUAD(kc0,set0); READ(P,kc1,set1); STG kc0(t+2)->P           | BAR
//  Z1: QUAD(kc1,set1); READ(P,kc2,set0); STG kc1(t+2)->P           | BAR
//  Z2: QUAD(kc2,set0); READ(P,kc3,set1); STG kc2(t+2)->P;
//      vmcnt(6|0)                                                   | BAR
//  Z3: QUAD(kc3,set1); READ(!P,kc0,set0) [t+1]; STG kc3(t+2)->P    | BAR
// vmcnt(6) at Z2-end: outstanding = {t-1.Z3: 2, t.Z0-Z2: 6}; wait<=6
// retires t-1.Z3 and (in-order) all older -> tile t+1 fully resident
// BEFORE Z3's pre-read. WAR: every stage >=1 barrier after its region's
// last reader (kc0: pre-read ZB(t-1); kc1/kc2: ZA/Z1(t); kc3: Z2(t)).
// No setprio: with 2 lockstep waves/SIMD, prio(1) on the MFMA wave starves
// the other wave's ds_reads (r18 A/B: +5pp MfmaUtil without it; cf. m190).
// Chunked XCD swizzle (FETCH 1.5->0.55 GB, r12) + nt-stores retained.
// ---------------------------------------------------------------------------
__global__ __launch_bounds__(512, 1)
void gemm_final(const unsigned short* __restrict__ xb,   // frag order
                const unsigned short* __restrict__ wt,   // frag order
                const float* __restrict__ bias,
                float* __restrict__ out) {
    constexpr int NT = IN_F / 64;  // 64 K-tiles
    constexpr int NKF = IN_F / 16; // 256 k-frags
    __shared__ __attribute__((aligned(128))) unsigned short lds[65536]; // 128 KiB

    // chunked XCD swizzle: XCD x owns m-band [4x,4x+4); n slow within band
    const int bid = (int)blockIdx.x;
    const int xcd = bid & 7;
    const int l   = bid >> 3;          // 0..171
    const int m0 = (xcd * 4 + (l & 3)) * 256;
    const int n0 = (l >> 2) * 256;

    const int tid  = threadIdx.x;
    const int lane = tid & 63;
    const int wave = tid >> 6;       // 0..7
    const int wr = wave >> 2;        // 0..1  (M half)
    const int wc = wave & 3;         // 0..3  (N quarter)
    const int r32 = lane & 31;
    const int q2  = lane >> 5;

    const ASG char* xbc = (const ASG char*)xb;
    const ASG char* wtc = (const ASG char*)wt;
    ASL char* ldsc = (ASL char*)lds;

    // ---- staging streams: stream kc stages subtile (f=wave, kc) of A and
    // (cf=wave, kc) of B; coalesced 1024-B bursts; +4096 B per use (1 tile).
    const int mfb = m0 >> 5;
    const int nfb = n0 >> 5;
    unsigned int oA[4], oB[4];
    int dA[4], dB[4];
#pragma unroll
    for (int kc = 0; kc < 4; ++kc) {
        oA[kc] = (unsigned int)(((mfb + wave) * NKF + kc) * 1024 + lane * 16);
        oB[kc] = (unsigned int)(((nfb + wave) * NKF + kc) * 1024 + lane * 16);
        dA[kc] = (wave * 4 + kc) * 1024;
        dB[kc] = 32768 + (wave * 4 + kc) * 1024;
    }

#define STG_Z(KC, P)                                                           \
    do {                                                                       \
        __builtin_amdgcn_global_load_lds(                                      \
            (ASG const unsigned int*)(xbc + oA[(KC)]),                         \
            (ASL unsigned int*)(ldsc + dA[(KC)] + (P) * 65536), 16, 0, 0);     \
        __builtin_amdgcn_global_load_lds(                                      \
            (ASG const unsigned int*)(wtc + oB[(KC)]),                         \
            (ASL unsigned int*)(ldsc + dB[(KC)] + (P) * 65536), 16, 0, 0);     \
        oA[(KC)] += 4096;                                                      \
        oB[(KC)] += 4096;                                                      \
    } while (0)

#define BAR()                                                                  \
    do {                                                                       \
        __builtin_amdgcn_sched_barrier(0);                                     \
        __builtin_amdgcn_s_barrier();                                          \
        __builtin_amdgcn_sched_barrier(0);                                     \
    } while (0)

    bf16x8 afR[2][4];   // [set][m-frag]
    bf16x8 bfR[2][2];   // [set][n-frag]
    f32x16 acc[4][2];
#pragma unroll
    for (int i = 0; i < 4; ++i)
#pragma unroll
        for (int j = 0; j < 2; ++j) acc[i][j] = (f32x16)0.0f;

    // read all 6 operand frags of one kc into register set S
#define READ_KC(P, KC, S)                                                      \
    do {                                                                       \
        const unsigned short* _b = lds + (P) * 32768 + lane * 8;               \
        _Pragma("unroll") for (int _m = 0; _m < 4; ++_m)                       \
            afR[S][_m] = *(const bf16x8*)(_b +                                 \
                (((wr * 4 + _m) * 4 + (KC)) << 9));                            \
        _Pragma("unroll") for (int _n = 0; _n < 2; ++_n)                       \
            bfR[S][_n] = *(const bf16x8*)(_b + 16384 +                         \
                (((wc * 2 + _n) * 4 + (KC)) << 9));                            \
    } while (0)

    // 8 INDEPENDENT MFMA — no setprio
#define QUAD_KC(S)                                                             \
    do {                                                                       \
        _Pragma("unroll") for (int _m = 0; _m < 4; ++_m)                       \
        _Pragma("unroll") for (int _n = 0; _n < 2; ++_n)                       \
            acc[_m][_n] = __builtin_amdgcn_mfma_f32_32x32x16_bf16(             \
                afR[S][_m], bfR[S][_n], acc[_m][_n], 0, 0, 0);                 \
    } while (0)

    // ---- prologue: stage tile0 then tile1 (8+8 insts); tile0 resident.
#pragma unroll
    for (int kc = 0; kc < 4; ++kc) STG_Z(kc, 0);
#pragma unroll
    for (int kc = 0; kc < 4; ++kc) STG_Z(kc, 1);
    __builtin_amdgcn_sched_barrier(0);
    asm volatile("s_waitcnt vmcnt(8)" ::: "memory");
    BAR();
    READ_KC(0, 0, 0);   // tile0 kc0 -> set0
    BAR();              // all waves done reading kc0 before Z0 stages over it

#pragma unroll 1
    for (int tt = 0; tt < NT; tt += 2) {
        const bool g2 = (tt + 2 < NT);
        const bool g3 = (tt + 3 < NT);
        // ================= tile tt (buf 0) =================
        // Z0
        QUAD_KC(0); READ_KC(0, 1, 1); if (g2) STG_Z(0, 0); BAR();
        // Z1
        QUAD_KC(1); READ_KC(0, 2, 0); if (g2) STG_Z(1, 0); BAR();
        // Z2 (+ counted vmcnt: tile tt+1 resident after)
        QUAD_KC(0); READ_KC(0, 3, 1); if (g2) STG_Z(2, 0);
        __builtin_amdgcn_sched_barrier(0);
        if (g2) {
            asm volatile("s_waitcnt vmcnt(6)" ::: "memory");
        } else {
            asm volatile("s_waitcnt vmcnt(0)" ::: "memory");
        }
        BAR();
        // Z3 (pre-read of tile tt+1 kc0 overlapped under QUAD)
        QUAD_KC(1);
        READ_KC(1, 0, 0);                  // tt+1 always exists (NT even)
        if (g2) STG_Z(3, 0);
        BAR();
        // ================= tile tt+1 (buf 1) =================
        // Z0
        QUAD_KC(0); READ_KC(1, 1, 1); if (g3) STG_Z(0, 1); BAR();
        // Z1
        QUAD_KC(1); READ_KC(1, 2, 0); if (g3) STG_Z(1, 1); BAR();
        // Z2
        QUAD_KC(0); READ_KC(1, 3, 1); if (g3) STG_Z(2, 1);
        __builtin_amdgcn_sched_barrier(0);
        if (g3) {
            asm volatile("s_waitcnt vmcnt(6)" ::: "memory");
        } else {
            asm volatile("s_waitcnt vmcnt(0)" ::: "memory");
        }
        BAR();
        // Z3
        QUAD_KC(1);
        if (g2) READ_KC(0, 0, 0);          // tile tt+2 kc0 -> set0
        if (g3) STG_Z(3, 1);
        BAR();
    }

    // ---- epilogue: 32x32 C/D layout col = lane&31,
    //      row = (reg&3) + 8*(reg>>2) + 4*(lane>>5); non-temporal stores.
#pragma unroll
    for (int nf = 0; nf < 2; ++nf) {
        const int col = n0 + wc * 64 + nf * 32 + r32;
        const float bv = bias[col];
#pragma unroll
        for (int mf = 0; mf < 4; ++mf) {
            const int row0 = m0 + wr * 128 + mf * 32 + q2 * 4;
#pragma unroll
            for (int r = 0; r < 16; ++r) {
                const int row = row0 + (r & 3) + ((r >> 2) << 3);
                __builtin_nontemporal_store(acc[mf][nf][r] + bv,
                                            &out[(size_t)row * OUT_F + col]);
            }
        }
    }
#undef STG_Z
#undef BAR
#undef READ_KC
#undef QUAD_KC
}

// ---------------------------------------------------------------------------
// Fallback GEMM (reg-staged 128x128, row-major operands), for small ws.
// ---------------------------------------------------------------------------
template <bool PREW>
__global__ __launch_bounds__(256, 2)
void gemm_kernel(const float* __restrict__ x,
                 const unsigned short* __restrict__ wt,
                 const int* __restrict__ qw,
                 const float* __restrict__ scales,
                 const float* __restrict__ zeros,
                 const float* __restrict__ bias,
                 float* __restrict__ out) {
    constexpr int BM = 128, BN = 128, BK = 64;
    constexpr int LDK = BK + 8;
    constexpr int NT = IN_F / BK;

    __shared__ unsigned short As[BM * LDK];
    __shared__ unsigned short Bs[BN * LDK];

    const int bid = blockIdx.x;
    constexpr int NB_N = OUT_F / BN;
    const int m0 = (bid / NB_N) * BM;
    const int n0 = (bid % NB_N) * BN;

    const int tid  = threadIdx.x;
    const int lane = tid & 63;
    const int wave = tid >> 6;
    const int wr = wave >> 1, wc = wave & 1;

    const int st_row = tid >> 3;
    const int st_col = (tid & 7) * 8;

    f32x4 areg[4][2];
    u32x4 breg[4];
    int   qreg[16];
    float s_, z_;
    const int b_n  = tid & 127;
    const int b_kp = (tid >> 7) * 16;

    auto load_tile = [&](int kt) {
        {
            const float* base = x + (size_t)m0 * IN_F + (size_t)kt * BK + st_col;
#pragma unroll
            for (int p = 0; p < 4; ++p) {
                const float* rp = base + (size_t)(p * 32 + st_row) * IN_F;
                areg[p][0] = *(const f32x4*)rp;
                areg[p][1] = *(const f32x4*)(rp + 4);
            }
        }
        if constexpr (PREW) {
            const unsigned short* base = wt + (size_t)n0 * IN_F + (size_t)kt * BK + st_col;
#pragma unroll
            for (int p = 0; p < 4; ++p)
                breg[p] = *(const u32x4*)(base + (size_t)(p * 32 + st_row) * IN_F);
        } else {
            const int kp0 = kt * (BK / 2) + b_kp;
#pragma unroll
            for (int i = 0; i < 16; ++i)
                qreg[i] = qw[(size_t)(kp0 + i) * OUT_F + n0 + b_n];
            const int g = (kt * BK) >> 7;
            s_ = scales[(size_t)g * OUT_F + n0 + b_n];
            z_ = zeros[(size_t)g * OUT_F + n0 + b_n];
        }
    };

    auto write_lds = [&]() {
#pragma unroll
        for (int p = 0; p < 4; ++p) {
            u16x8 v;
#pragma unroll
            for (int e = 0; e < 4; ++e) {
                v[e]     = f2bf(areg[p][0][e]);
                v[e + 4] = f2bf(areg[p][1][e]);
            }
            *(u16x8*)(&As[(p * 32 + st_row) * LDK + st_col]) = v;
        }
        if constexpr (PREW) {
#pragma unroll
            for (int p = 0; p < 4; ++p)
                *(u32x4*)(&Bs[(p * 32 + st_row) * LDK + st_col]) = breg[p];
        } else {
            unsigned short tmp[32];
#pragma unroll
            for (int i = 0; i < 16; ++i) {
                int q = qreg[i];
                tmp[2 * i]     = f2bf((float)((q & 15) - 8) * s_ + z_);
                tmp[2 * i + 1] = f2bf((float)(((q >> 4) & 15) - 8) * s_ + z_);
            }
            const u16x8* srcv = (const u16x8*)tmp;
#pragma unroll
            for (int i = 0; i < 4; ++i)
                *(u16x8*)(&Bs[b_n * LDK + 2 * b_kp + 8 * i]) = srcv[i];
        }
    };

    f32x4 acc[4][4];
#pragma unroll
    for (int i = 0; i < 4; ++i)
#pragma unroll
        for (int j = 0; j < 4; ++j) acc[i][j] = (f32x4)0.0f;

    load_tile(0);

#pragma unroll 1
    for (int kt = 0; kt < NT; ++kt) {
        __syncthreads();
        write_lds();
        __syncthreads();
        if (kt + 1 < NT) load_tile(kt + 1);

#pragma unroll
        for (int kk = 0; kk < 2; ++kk) {
            const int kidx = kk * 32 + ((lane >> 4) << 3);
            bf16x8 afv[4], bfv[4];
#pragma unroll
            for (int i = 0; i < 4; ++i)
                afv[i] = *(const bf16x8*)(&As[(wr * 64 + i * 16 + (lane & 15)) * LDK + kidx]);
#pragma unroll
            for (int j = 0; j < 4; ++j)
                bfv[j] = *(const bf16x8*)(&Bs[(wc * 64 + j * 16 + (lane & 15)) * LDK + kidx]);
#pragma unroll
            for (int i = 0; i < 4; ++i)
#pragma unroll
                for (int j = 0; j < 4; ++j)
                    acc[i][j] = __builtin_amdgcn_mfma_f32_16x16x32_bf16(afv[i], bfv[j], acc[i][j], 0, 0, 0);
        }
    }

    const int orow_base = m0 + wr * 64 + ((lane >> 4) << 2);
    const int ocol_base = n0 + wc * 64 + (lane & 15);
#pragma unroll
    for (int j = 0; j < 4; ++j) {
        const float bv = bias[ocol_base + j * 16];
#pragma unroll
        for (int i = 0; i < 4; ++i) {
#pragma unroll
            for (int q = 0; q < 4; ++q) {
                out[(size_t)(orow_base + i * 16 + q) * OUT_F + (ocol_base + j * 16)] =
                    acc[i][j][q] + bv;
            }
        }
    }
}

// ---------------------------------------------------------------------------
extern "C" void kernel_launch(void* const* d_in, const int* in_sizes, int n_in,
                              void* d_out, int out_size, void* d_ws, size_t ws_size,
                              hipStream_t stream) {
    const float* x      = (const float*)d_in[0];
    const int*   qw     = (const int*)d_in[1];
    const float* scales = (const float*)d_in[2];
    const float* zeros  = (const float*)d_in[3];
    const float* bias   = (const float*)d_in[4];
    float* out = (float*)d_out;

    const size_t wt_bytes = (size_t)OUT_F * IN_F * sizeof(unsigned short);   // 90.2 MB
    const size_t xb_bytes = (size_t)M_TOTAL * IN_F * sizeof(unsigned short); // 67.1 MB

    if (ws_size >= wt_bytes + xb_bytes) {
        unsigned short* wt = (unsigned short*)d_ws;
        unsigned short* xb = (unsigned short*)((char*)d_ws + wt_bytes);
        convert_x_frag_kernel<<<dim3(M_TOTAL / 32, 8), 256, 0, stream>>>(x, xb);
        dequant_w_frag_kernel<<<dim3(OUT_F / 256, IN_F / 32), 256, 0, stream>>>(qw, scales, zeros, wt);
        gemm_final<<<(M_TOTAL / 256) * (OUT_F / 256), 512, 0, stream>>>(xb, wt, bias, out);
    } else if (ws_size >= wt_bytes) {
        unsigned short* wt = (unsigned short*)d_ws;
        dequant_w_rowmajor_kernel<<<dim3(OUT_F / 256, IN_F / 32), 256, 0, stream>>>(qw, scales, zeros, wt);
        gemm_kernel<true><<<(M_TOTAL / 128) * (OUT_F / 128), 256, 0, stream>>>(x, wt, qw, scales, zeros, bias, out);
    } else {
        gemm_kernel<false><<<(M_TOTAL / 128) * (OUT_F / 128), 256, 0, stream>>>(x, nullptr, qw, scales, zeros, bias, out);
    }
}